// Round 5
// baseline (1916.402 us; speedup 1.0000x reference)
//
#include <hip/hip_runtime.h>
#include <math.h>

#define ND 256
#define RPB 48            // rows per block (48 | 576)
#define RPW 12            // rows per wave (4 waves)
#define ROWS_PER_B 576
#define BATCH 512
#define NBLOCKS (BATCH * ROWS_PER_B / RPB)   // 6144

// itertools.permutations(range(4)) — lexicographic order, with parity signs
__constant__ int c_P[24 * 4] = {
    0,1,2,3, 0,1,3,2, 0,2,1,3, 0,2,3,1, 0,3,1,2, 0,3,2,1,
    1,0,2,3, 1,0,3,2, 1,2,0,3, 1,2,3,0, 1,3,0,2, 1,3,2,0,
    2,0,1,3, 2,0,3,1, 2,1,0,3, 2,1,3,0, 2,3,0,1, 2,3,1,0,
    3,0,1,2, 3,0,2,1, 3,1,0,2, 3,1,2,0, 3,2,0,1, 3,2,1,0
};
__constant__ float c_S[24] = {
     1.f,-1.f,-1.f, 1.f, 1.f,-1.f,
    -1.f, 1.f, 1.f,-1.f,-1.f, 1.f,
     1.f,-1.f,-1.f, 1.f, 1.f,-1.f,
    -1.f, 1.f, 1.f,-1.f,-1.f, 1.f
};

__device__ __forceinline__ float bcast(float v, int srcLane) {
    return __int_as_float(__builtin_amdgcn_readlane(__float_as_int(v), srcLane));
}

// LDS budget 50368 B -> 3 blocks/CU. Y never touches LDS during GEMMs:
// each wave's 12 rows live in registers; y[k] is wave-broadcast via readlane
// (identical fp32 FMA chain order as np-mimicking baseline).
__global__ __launch_bounds__(256, 3)
void fused_resnet(const float* __restrict__ x1, const float* __restrict__ x2,
                  const float* __restrict__ W0, const float* __restrict__ b0,
                  const float* __restrict__ W1, const float* __restrict__ b1,
                  const float* __restrict__ W2, const float* __restrict__ b2,
                  const float* __restrict__ Wf, const float* __restrict__ bf,
                  double* __restrict__ anti)
{
    __shared__ __align__(16) float smem[12592];  // 50368 B
    float* sW  = smem;            // [32][256] W tile (32 KB)
    float* sF  = smem + 8192;     // [48][24] feats (L0 only)
    float* sWf = smem + 12336;    // [256] head weights (never overwritten)
    // head phase reuses smem[0..12336) as [48][257] f32 Y dump

    const int t    = threadIdx.x;
    const int lane = t & 63;
    const int wv   = t >> 6;          // wave 0..3
    const int r0   = wv * RPW;        // this wave's first row
    const int gr0  = blockIdx.x * RPB;
    const int b    = gr0 / ROWS_PER_B;

    // ---- feats into sF ----
    for (int i = t; i < RPB * 24; i += 256) {
        int lr = i / 24, c = i % 24;
        int pp = (gr0 + lr) % ROWS_PER_B;
        float v;
        if (c < 12) {
            v = x1[b * 12 + c_P[(pp / 24) * 4 + c / 3] * 3 + (c % 3)];
        } else {
            int cc = c - 12;
            v = x2[b * 12 + c_P[(pp % 24) * 4 + cc / 3] * 3 + (cc % 3)];
        }
        sF[i] = v;
    }
    {   // stage W0 (24 rows = 6144 f32)
        const float4* src = (const float4*)W0;
        float4* dst = (float4*)sW;
        #pragma unroll
        for (int i = 0; i < 6; ++i) dst[t + 256 * i] = src[t + 256 * i];
    }
    if (t < 64) ((float4*)sWf)[t] = ((const float4*)Wf)[t];
    __syncthreads();

    float acc[RPW][4];   // this lane's cols 4*lane..4*lane+3 of its wave's rows
    float y[RPW][4];

    // ---------- layer 0: 24 -> 256, tanh, no residual ----------
    #pragma unroll
    for (int r = 0; r < RPW; ++r) { acc[r][0]=0.f; acc[r][1]=0.f; acc[r][2]=0.f; acc[r][3]=0.f; }
    #pragma unroll
    for (int k4 = 0; k4 < 6; ++k4) {
        float4 w[4];
        #pragma unroll
        for (int kk = 0; kk < 4; ++kk)
            w[kk] = *(const float4*)&sW[(k4 * 4 + kk) * ND + 4 * lane];
        #pragma unroll
        for (int r = 0; r < RPW; ++r) {
            float4 yv = *(const float4*)&sF[(r0 + r) * 24 + k4 * 4];
            float yk[4] = {yv.x, yv.y, yv.z, yv.w};
            #pragma unroll
            for (int kk = 0; kk < 4; ++kk) {
                acc[r][0] = fmaf(yk[kk], w[kk].x, acc[r][0]);
                acc[r][1] = fmaf(yk[kk], w[kk].y, acc[r][1]);
                acc[r][2] = fmaf(yk[kk], w[kk].z, acc[r][2]);
                acc[r][3] = fmaf(yk[kk], w[kk].w, acc[r][3]);
            }
        }
    }
    {
        float4 bv = *(const float4*)&b0[4 * lane];
        #pragma unroll
        for (int r = 0; r < RPW; ++r) {
            y[r][0] = tanhf(acc[r][0] + bv.x);
            y[r][1] = tanhf(acc[r][1] + bv.y);
            y[r][2] = tanhf(acc[r][2] + bv.z);
            y[r][3] = tanhf(acc[r][3] + bv.w);
        }
    }

    // ---------- layers 1,2: 256 -> 256, tanh + residual ----------
    #pragma unroll 1
    for (int L = 0; L < 2; ++L) {
        const float* __restrict__ Wg = L ? W2 : W1;
        const float* __restrict__ bp = L ? b2 : b1;
        #pragma unroll
        for (int r = 0; r < RPW; ++r) { acc[r][0]=0.f; acc[r][1]=0.f; acc[r][2]=0.f; acc[r][3]=0.f; }
        #pragma unroll 1
        for (int T = 0; T < 8; ++T) {          // 32 K-rows per tile
            __syncthreads();                   // prior tile reads done
            {
                const float4* src = (const float4*)(Wg + T * 32 * ND);
                float4* dst = (float4*)sW;
                #pragma unroll
                for (int i = 0; i < 8; ++i) dst[t + 256 * i] = src[t + 256 * i];
            }
            __syncthreads();
            float4 wc[4], wn[4];
            #pragma unroll
            for (int kk = 0; kk < 4; ++kk)
                wc[kk] = *(const float4*)&sW[kk * ND + 4 * lane];
            #pragma unroll 1
            for (int k4 = 0; k4 < 8; ++k4) {
                if (k4 < 7) {                  // prefetch next k4's W fragment
                    #pragma unroll
                    for (int kk = 0; kk < 4; ++kk)
                        wn[kk] = *(const float4*)&sW[((k4 + 1) * 4 + kk) * ND + 4 * lane];
                }
                const int sl = T * 8 + k4;     // owner lane of y[k..k+3]
                #pragma unroll
                for (int r = 0; r < RPW; ++r) {
                    float ys[4];
                    #pragma unroll
                    for (int kk = 0; kk < 4; ++kk) ys[kk] = bcast(y[r][kk], sl);
                    #pragma unroll
                    for (int kk = 0; kk < 4; ++kk) {
                        acc[r][0] = fmaf(ys[kk], wc[kk].x, acc[r][0]);
                        acc[r][1] = fmaf(ys[kk], wc[kk].y, acc[r][1]);
                        acc[r][2] = fmaf(ys[kk], wc[kk].z, acc[r][2]);
                        acc[r][3] = fmaf(ys[kk], wc[kk].w, acc[r][3]);
                    }
                }
                #pragma unroll
                for (int kk = 0; kk < 4; ++kk) wc[kk] = wn[kk];
            }
        }
        float4 bv = *(const float4*)&bp[4 * lane];
        #pragma unroll
        for (int r = 0; r < RPW; ++r) {
            y[r][0] = tanhf(acc[r][0] + bv.x) + y[r][0];
            y[r][1] = tanhf(acc[r][1] + bv.y) + y[r][1];
            y[r][2] = tanhf(acc[r][2] + bv.z) + y[r][2];
            y[r][3] = tanhf(acc[r][3] + bv.w) + y[r][3];
        }
    }

    // ---------- head: dump Y to LDS, per-row fp32 chain, f64 signed sum ----
    __syncthreads();                 // all sW reads done; smem becomes Y dump
    #pragma unroll
    for (int r = 0; r < RPW; ++r) {
        int row = r0 + r;
        smem[row * 257 + 4 * lane + 0] = y[r][0];
        smem[row * 257 + 4 * lane + 1] = y[r][1];
        smem[row * 257 + 4 * lane + 2] = y[r][2];
        smem[row * 257 + 4 * lane + 3] = y[r][3];
    }
    __syncthreads();
    double contrib = 0.0;
    if (t < RPB) {
        const float* yrow = &smem[t * 257];
        float f = 0.f;
        #pragma unroll 8
        for (int k = 0; k < ND; ++k) f = fmaf(yrow[k], sWf[k], f);
        f += bf[0];
        int pp = (gr0 + t) % ROWS_PER_B;
        contrib = (double)(c_S[pp / 24] * c_S[pp % 24]) * (double)f;
    }
    if (wv == 0) {
        #pragma unroll
        for (int off = 32; off > 0; off >>= 1) contrib += __shfl_xor(contrib, off, 64);
        if (lane == 0) atomicAdd(&anti[b], contrib);
    }
}

__global__ void finalize_log(const double* __restrict__ anti, float* __restrict__ out) {
    int i = blockIdx.x * 256 + threadIdx.x;
    if (i < BATCH) out[i] = (float)log(fabs(anti[i]));
}

extern "C" void kernel_launch(void* const* d_in, const int* in_sizes, int n_in,
                              void* d_out, int out_size, void* d_ws, size_t ws_size,
                              hipStream_t stream) {
    const float* x1 = (const float*)d_in[0];
    const float* x2 = (const float*)d_in[1];
    const float* W0 = (const float*)d_in[2];
    const float* b0 = (const float*)d_in[3];
    const float* W1 = (const float*)d_in[4];
    const float* b1 = (const float*)d_in[5];
    const float* W2 = (const float*)d_in[6];
    const float* b2 = (const float*)d_in[7];
    const float* Wf = (const float*)d_in[8];
    const float* bf = (const float*)d_in[9];
    double* anti = (double*)d_ws;                   // 512 doubles of scratch
    float* out   = (float*)d_out;

    (void)hipMemsetAsync(anti, 0, BATCH * sizeof(double), stream);
    fused_resnet<<<NBLOCKS, 256, 0, stream>>>(x1, x2, W0, b0, W1, b1, W2, b2, Wf, bf, anti);
    finalize_log<<<(BATCH + 255) / 256, 256, 0, stream>>>(anti, out);
}

// Round 6
// 1715.796 us; speedup vs baseline: 1.1169x; 1.1169x over previous
//
#include <hip/hip_runtime.h>
#include <math.h>

#define ND 256
#define RPB 32            // rows per block (32 | 576 via 9216 blocks)
#define RPW 8             // rows per wave (4 waves)
#define ROWS_PER_B 576
#define BATCH 512
#define NBLOCKS (BATCH * ROWS_PER_B / RPB)   // 9216

// itertools.permutations(range(4)) — lexicographic order, with parity signs
__constant__ int c_P[24 * 4] = {
    0,1,2,3, 0,1,3,2, 0,2,1,3, 0,2,3,1, 0,3,1,2, 0,3,2,1,
    1,0,2,3, 1,0,3,2, 1,2,0,3, 1,2,3,0, 1,3,0,2, 1,3,2,0,
    2,0,1,3, 2,0,3,1, 2,1,0,3, 2,1,3,0, 2,3,0,1, 2,3,1,0,
    3,0,1,2, 3,0,2,1, 3,1,0,2, 3,1,2,0, 3,2,0,1, 3,2,1,0
};
__constant__ float c_S[24] = {
     1.f,-1.f,-1.f, 1.f, 1.f,-1.f,
    -1.f, 1.f, 1.f,-1.f,-1.f, 1.f,
     1.f,-1.f,-1.f, 1.f, 1.f,-1.f,
    -1.f, 1.f, 1.f,-1.f,-1.f, 1.f
};

__device__ __forceinline__ float bcast(float v, int srcLane) {
    return __int_as_float(__builtin_amdgcn_readlane(__float_as_int(v), srcLane));
}

// Y lives in registers (8 rows x 4 cols per lane); y[k] is wave-broadcast via
// v_readlane -> SGPR operand of v_fma_f32. Identical fp32 chain order as the
// passing baseline. LDS carries only the W tile (36.9 KB -> 4 blocks/CU).
// launch_bounds(256,2): 256-VGPR cap so ~120 live regs NEVER spill (round-5
// lesson: (256,3)'s 168 cap demoted acc/y to scratch -> 2.8 GB HBM traffic).
__global__ __launch_bounds__(256, 2)
void fused_resnet(const float* __restrict__ x1, const float* __restrict__ x2,
                  const float* __restrict__ W0, const float* __restrict__ b0,
                  const float* __restrict__ W1, const float* __restrict__ b1,
                  const float* __restrict__ W2, const float* __restrict__ b2,
                  const float* __restrict__ Wf, const float* __restrict__ bf,
                  double* __restrict__ anti)
{
    __shared__ __align__(16) float smem[9216];   // 36864 B
    float* sW  = smem;            // [32][256] W tile (32 KB)
    float* sF  = smem + 8192;     // [32][24] feats (L0 only)
    float* sWf = smem + 8960;     // [256] head weights (never overwritten)
    // head phase reuses smem[0..8224) as [32][257] f32 Y dump

    const int t    = threadIdx.x;
    const int lane = t & 63;
    const int wv   = t >> 6;          // wave 0..3
    const int r0   = wv * RPW;        // this wave's first row
    const int gr0  = blockIdx.x * RPB;
    const int b    = gr0 / ROWS_PER_B;

    // ---- feats into sF ----
    for (int i = t; i < RPB * 24; i += 256) {
        int lr = i / 24, c = i % 24;
        int pp = (gr0 + lr) % ROWS_PER_B;
        float v;
        if (c < 12) {
            v = x1[b * 12 + c_P[(pp / 24) * 4 + c / 3] * 3 + (c % 3)];
        } else {
            int cc = c - 12;
            v = x2[b * 12 + c_P[(pp % 24) * 4 + cc / 3] * 3 + (cc % 3)];
        }
        sF[i] = v;
    }
    {   // stage W0 (24 rows = 6144 f32)
        const float4* src = (const float4*)W0;
        float4* dst = (float4*)sW;
        #pragma unroll
        for (int i = 0; i < 6; ++i) dst[t + 256 * i] = src[t + 256 * i];
    }
    if (t < 64) ((float4*)sWf)[t] = ((const float4*)Wf)[t];
    __syncthreads();

    float acc[RPW][4];   // this lane's cols 4*lane..4*lane+3 of its wave's rows
    float y[RPW][4];

    // ---------- layer 0: 24 -> 256, tanh, no residual ----------
    #pragma unroll
    for (int r = 0; r < RPW; ++r) { acc[r][0]=0.f; acc[r][1]=0.f; acc[r][2]=0.f; acc[r][3]=0.f; }
    #pragma unroll
    for (int k4 = 0; k4 < 6; ++k4) {
        float4 w[4];
        #pragma unroll
        for (int kk = 0; kk < 4; ++kk)
            w[kk] = *(const float4*)&sW[(k4 * 4 + kk) * ND + 4 * lane];
        #pragma unroll
        for (int r = 0; r < RPW; ++r) {
            float4 yv = *(const float4*)&sF[(r0 + r) * 24 + k4 * 4];
            float yk[4] = {yv.x, yv.y, yv.z, yv.w};
            #pragma unroll
            for (int kk = 0; kk < 4; ++kk) {
                acc[r][0] = fmaf(yk[kk], w[kk].x, acc[r][0]);
                acc[r][1] = fmaf(yk[kk], w[kk].y, acc[r][1]);
                acc[r][2] = fmaf(yk[kk], w[kk].z, acc[r][2]);
                acc[r][3] = fmaf(yk[kk], w[kk].w, acc[r][3]);
            }
        }
    }
    {
        float4 bv = *(const float4*)&b0[4 * lane];
        #pragma unroll
        for (int r = 0; r < RPW; ++r) {
            y[r][0] = tanhf(acc[r][0] + bv.x);
            y[r][1] = tanhf(acc[r][1] + bv.y);
            y[r][2] = tanhf(acc[r][2] + bv.z);
            y[r][3] = tanhf(acc[r][3] + bv.w);
        }
    }

    // ---------- layers 1,2: 256 -> 256, tanh + residual ----------
    auto LDW = [&](float4 w[4], int k4) {
        #pragma unroll
        for (int kk = 0; kk < 4; ++kk)
            w[kk] = *(const float4*)&sW[(k4 * 4 + kk) * ND + 4 * lane];
    };
    auto STEP = [&](const float4 w[4], int sl) {
        #pragma unroll
        for (int r = 0; r < RPW; ++r) {
            float ys[4];
            #pragma unroll
            for (int kk = 0; kk < 4; ++kk) ys[kk] = bcast(y[r][kk], sl);
            #pragma unroll
            for (int kk = 0; kk < 4; ++kk) {
                acc[r][0] = fmaf(ys[kk], w[kk].x, acc[r][0]);
                acc[r][1] = fmaf(ys[kk], w[kk].y, acc[r][1]);
                acc[r][2] = fmaf(ys[kk], w[kk].z, acc[r][2]);
                acc[r][3] = fmaf(ys[kk], w[kk].w, acc[r][3]);
            }
        }
    };

    #pragma unroll 1
    for (int L = 0; L < 2; ++L) {
        const float* __restrict__ Wg = L ? W2 : W1;
        const float* __restrict__ bp = L ? b2 : b1;
        #pragma unroll
        for (int r = 0; r < RPW; ++r) { acc[r][0]=0.f; acc[r][1]=0.f; acc[r][2]=0.f; acc[r][3]=0.f; }
        #pragma unroll 1
        for (int T = 0; T < 8; ++T) {          // 32 K-rows per tile
            __syncthreads();                   // prior tile reads done
            {
                const float4* src = (const float4*)(Wg + T * 32 * ND);
                float4* dst = (float4*)sW;
                #pragma unroll
                for (int i = 0; i < 8; ++i) dst[t + 256 * i] = src[t + 256 * i];
            }
            __syncthreads();
            float4 wA[4], wB[4];
            LDW(wA, 0);
            #pragma unroll 1
            for (int k4 = 0; k4 < 8; k4 += 2) {   // ping-pong, no reg copies
                LDW(wB, k4 + 1);
                STEP(wA, T * 8 + k4);
                if (k4 + 2 < 8) LDW(wA, k4 + 2);
                STEP(wB, T * 8 + k4 + 1);
            }
        }
        float4 bv = *(const float4*)&bp[4 * lane];
        #pragma unroll
        for (int r = 0; r < RPW; ++r) {
            y[r][0] = tanhf(acc[r][0] + bv.x) + y[r][0];
            y[r][1] = tanhf(acc[r][1] + bv.y) + y[r][1];
            y[r][2] = tanhf(acc[r][2] + bv.z) + y[r][2];
            y[r][3] = tanhf(acc[r][3] + bv.w) + y[r][3];
        }
    }

    // ---------- head: dump Y to LDS, per-row fp32 chain, f64 signed sum ----
    __syncthreads();                 // all sW reads done; smem becomes Y dump
    #pragma unroll
    for (int r = 0; r < RPW; ++r) {
        int row = r0 + r;
        smem[row * 257 + 4 * lane + 0] = y[r][0];
        smem[row * 257 + 4 * lane + 1] = y[r][1];
        smem[row * 257 + 4 * lane + 2] = y[r][2];
        smem[row * 257 + 4 * lane + 3] = y[r][3];
    }
    __syncthreads();
    double contrib = 0.0;
    if (t < RPB) {
        const float* yrow = &smem[t * 257];
        float f = 0.f;
        #pragma unroll 8
        for (int k = 0; k < ND; ++k) f = fmaf(yrow[k], sWf[k], f);
        f += bf[0];
        int pp = (gr0 + t) % ROWS_PER_B;
        contrib = (double)(c_S[pp / 24] * c_S[pp % 24]) * (double)f;
    }
    if (wv == 0) {
        #pragma unroll
        for (int off = 32; off > 0; off >>= 1) contrib += __shfl_xor(contrib, off, 64);
        if (lane == 0) atomicAdd(&anti[b], contrib);
    }
}

__global__ void finalize_log(const double* __restrict__ anti, float* __restrict__ out) {
    int i = blockIdx.x * 256 + threadIdx.x;
    if (i < BATCH) out[i] = (float)log(fabs(anti[i]));
}

extern "C" void kernel_launch(void* const* d_in, const int* in_sizes, int n_in,
                              void* d_out, int out_size, void* d_ws, size_t ws_size,
                              hipStream_t stream) {
    const float* x1 = (const float*)d_in[0];
    const float* x2 = (const float*)d_in[1];
    const float* W0 = (const float*)d_in[2];
    const float* b0 = (const float*)d_in[3];
    const float* W1 = (const float*)d_in[4];
    const float* b1 = (const float*)d_in[5];
    const float* W2 = (const float*)d_in[6];
    const float* b2 = (const float*)d_in[7];
    const float* Wf = (const float*)d_in[8];
    const float* bf = (const float*)d_in[9];
    double* anti = (double*)d_ws;                   // 512 doubles of scratch
    float* out   = (float*)d_out;

    (void)hipMemsetAsync(anti, 0, BATCH * sizeof(double), stream);
    fused_resnet<<<NBLOCKS, 256, 0, stream>>>(x1, x2, W0, b0, W1, b1, W2, b2, Wf, bf, anti);
    finalize_log<<<(BATCH + 255) / 256, 256, 0, stream>>>(anti, out);
}

// Round 7
// 1351.972 us; speedup vs baseline: 1.4175x; 1.2691x over previous
//
#include <hip/hip_runtime.h>
#include <math.h>

#define ND 256
#define RPB 32            // rows per block (32 | 576 via 9216 blocks)
#define RPW 8             // rows per wave (4 waves)
#define ROWS_PER_B 576
#define BATCH 512
#define NBLOCKS (BATCH * ROWS_PER_B / RPB)   // 9216

// itertools.permutations(range(4)) — lexicographic order, with parity signs
__constant__ int c_P[24 * 4] = {
    0,1,2,3, 0,1,3,2, 0,2,1,3, 0,2,3,1, 0,3,1,2, 0,3,2,1,
    1,0,2,3, 1,0,3,2, 1,2,0,3, 1,2,3,0, 1,3,0,2, 1,3,2,0,
    2,0,1,3, 2,0,3,1, 2,1,0,3, 2,1,3,0, 2,3,0,1, 2,3,1,0,
    3,0,1,2, 3,0,2,1, 3,1,0,2, 3,1,2,0, 3,2,0,1, 3,2,1,0
};
__constant__ float c_S[24] = {
     1.f,-1.f,-1.f, 1.f, 1.f,-1.f,
    -1.f, 1.f, 1.f,-1.f,-1.f, 1.f,
     1.f,-1.f,-1.f, 1.f, 1.f,-1.f,
    -1.f, 1.f, 1.f,-1.f,-1.f, 1.f
};

__device__ __forceinline__ float bcast(float v, int srcLane) {
    return __int_as_float(__builtin_amdgcn_readlane(__float_as_int(v), srcLane));
}

// Y lives in registers (8 rows x 4 cols per lane); y[k] is wave-broadcast via
// v_readlane -> SGPR operand of v_fma_f32 (SGPR values cost no VGPRs).
// Identical fp32 chain order as the passing baseline.
// Round-6 lesson: the ping-pong W double-buffer (+32 VGPR) pushed the live set
// just past the compiler's 128 target -> 490 MB scratch. Single W buffer keeps
// ~100 live regs; VGPR<=128 -> 16 waves/CU (4 blocks x 36.9 KB LDS = 147 KB),
// and 4 waves/SIMD hide the per-k4 ds_read latency instead of ILP prefetch.
__global__ __launch_bounds__(256, 2)
void fused_resnet(const float* __restrict__ x1, const float* __restrict__ x2,
                  const float* __restrict__ W0, const float* __restrict__ b0,
                  const float* __restrict__ W1, const float* __restrict__ b1,
                  const float* __restrict__ W2, const float* __restrict__ b2,
                  const float* __restrict__ Wf, const float* __restrict__ bf,
                  double* __restrict__ anti)
{
    __shared__ __align__(16) float smem[9216];   // 36864 B
    float* sW  = smem;            // [32][256] W tile (32 KB)
    float* sF  = smem + 8192;     // [32][24] feats (L0 only)
    float* sWf = smem + 8960;     // [256] head weights (never overwritten)
    // head phase reuses smem[0..8224) as [32][257] f32 Y dump

    const int t    = threadIdx.x;
    const int lane = t & 63;
    const int wv   = t >> 6;          // wave 0..3
    const int r0   = wv * RPW;        // this wave's first row
    const int gr0  = blockIdx.x * RPB;
    const int b    = gr0 / ROWS_PER_B;

    // ---- feats into sF ----
    for (int i = t; i < RPB * 24; i += 256) {
        int lr = i / 24, c = i % 24;
        int pp = (gr0 + lr) % ROWS_PER_B;
        float v;
        if (c < 12) {
            v = x1[b * 12 + c_P[(pp / 24) * 4 + c / 3] * 3 + (c % 3)];
        } else {
            int cc = c - 12;
            v = x2[b * 12 + c_P[(pp % 24) * 4 + cc / 3] * 3 + (cc % 3)];
        }
        sF[i] = v;
    }
    {   // stage W0 (24 rows = 6144 f32)
        const float4* src = (const float4*)W0;
        float4* dst = (float4*)sW;
        #pragma unroll
        for (int i = 0; i < 6; ++i) dst[t + 256 * i] = src[t + 256 * i];
    }
    if (t < 64) ((float4*)sWf)[t] = ((const float4*)Wf)[t];
    __syncthreads();

    float acc[RPW][4];   // this lane's cols 4*lane..4*lane+3 of its wave's rows
    float y[RPW][4];

    // ---------- layer 0: 24 -> 256, tanh, no residual ----------
    #pragma unroll
    for (int r = 0; r < RPW; ++r) { acc[r][0]=0.f; acc[r][1]=0.f; acc[r][2]=0.f; acc[r][3]=0.f; }
    #pragma unroll 1
    for (int k4 = 0; k4 < 6; ++k4) {
        const float4* wp = (const float4*)&sW[(k4 * 4) * ND] + lane;
        float4 w0 = wp[0], w1 = wp[64], w2 = wp[128], w3 = wp[192];
        #pragma unroll
        for (int r = 0; r < RPW; ++r) {
            float4 yv = *(const float4*)&sF[(r0 + r) * 24 + k4 * 4];
            acc[r][0] = fmaf(yv.x, w0.x, acc[r][0]);
            acc[r][1] = fmaf(yv.x, w0.y, acc[r][1]);
            acc[r][2] = fmaf(yv.x, w0.z, acc[r][2]);
            acc[r][3] = fmaf(yv.x, w0.w, acc[r][3]);
            acc[r][0] = fmaf(yv.y, w1.x, acc[r][0]);
            acc[r][1] = fmaf(yv.y, w1.y, acc[r][1]);
            acc[r][2] = fmaf(yv.y, w1.z, acc[r][2]);
            acc[r][3] = fmaf(yv.y, w1.w, acc[r][3]);
            acc[r][0] = fmaf(yv.z, w2.x, acc[r][0]);
            acc[r][1] = fmaf(yv.z, w2.y, acc[r][1]);
            acc[r][2] = fmaf(yv.z, w2.z, acc[r][2]);
            acc[r][3] = fmaf(yv.z, w2.w, acc[r][3]);
            acc[r][0] = fmaf(yv.w, w3.x, acc[r][0]);
            acc[r][1] = fmaf(yv.w, w3.y, acc[r][1]);
            acc[r][2] = fmaf(yv.w, w3.z, acc[r][2]);
            acc[r][3] = fmaf(yv.w, w3.w, acc[r][3]);
        }
    }
    {
        float4 bv = *(const float4*)&b0[4 * lane];
        #pragma unroll
        for (int r = 0; r < RPW; ++r) {
            y[r][0] = tanhf(acc[r][0] + bv.x);
            y[r][1] = tanhf(acc[r][1] + bv.y);
            y[r][2] = tanhf(acc[r][2] + bv.z);
            y[r][3] = tanhf(acc[r][3] + bv.w);
        }
    }

    // ---------- layers 1,2: 256 -> 256, tanh + residual ----------
    #pragma unroll 1
    for (int L = 0; L < 2; ++L) {
        const float* __restrict__ Wg = L ? W2 : W1;
        const float* __restrict__ bp = L ? b2 : b1;
        #pragma unroll
        for (int r = 0; r < RPW; ++r) { acc[r][0]=0.f; acc[r][1]=0.f; acc[r][2]=0.f; acc[r][3]=0.f; }
        #pragma unroll 1
        for (int T = 0; T < 8; ++T) {          // 32 K-rows per tile
            __syncthreads();                   // prior tile reads done
            {
                const float4* src = (const float4*)(Wg + T * 32 * ND);
                float4* dst = (float4*)sW;
                #pragma unroll
                for (int i = 0; i < 8; ++i) dst[t + 256 * i] = src[t + 256 * i];
            }
            __syncthreads();
            #pragma unroll 1
            for (int k4 = 0; k4 < 8; ++k4) {
                const float4* wp = (const float4*)&sW[(k4 * 4) * ND] + lane;
                float4 w0 = wp[0], w1 = wp[64], w2 = wp[128], w3 = wp[192];
                const int sl = T * 8 + k4;     // owner lane of y[4k..4k+3]
                #pragma unroll
                for (int r = 0; r < RPW; ++r) {
                    float s0 = bcast(y[r][0], sl);
                    float s1 = bcast(y[r][1], sl);
                    float s2 = bcast(y[r][2], sl);
                    float s3 = bcast(y[r][3], sl);
                    acc[r][0] = fmaf(s0, w0.x, acc[r][0]);
                    acc[r][1] = fmaf(s0, w0.y, acc[r][1]);
                    acc[r][2] = fmaf(s0, w0.z, acc[r][2]);
                    acc[r][3] = fmaf(s0, w0.w, acc[r][3]);
                    acc[r][0] = fmaf(s1, w1.x, acc[r][0]);
                    acc[r][1] = fmaf(s1, w1.y, acc[r][1]);
                    acc[r][2] = fmaf(s1, w1.z, acc[r][2]);
                    acc[r][3] = fmaf(s1, w1.w, acc[r][3]);
                    acc[r][0] = fmaf(s2, w2.x, acc[r][0]);
                    acc[r][1] = fmaf(s2, w2.y, acc[r][1]);
                    acc[r][2] = fmaf(s2, w2.z, acc[r][2]);
                    acc[r][3] = fmaf(s2, w2.w, acc[r][3]);
                    acc[r][0] = fmaf(s3, w3.x, acc[r][0]);
                    acc[r][1] = fmaf(s3, w3.y, acc[r][1]);
                    acc[r][2] = fmaf(s3, w3.z, acc[r][2]);
                    acc[r][3] = fmaf(s3, w3.w, acc[r][3]);
                }
            }
        }
        float4 bv = *(const float4*)&bp[4 * lane];
        #pragma unroll
        for (int r = 0; r < RPW; ++r) {
            y[r][0] = tanhf(acc[r][0] + bv.x) + y[r][0];
            y[r][1] = tanhf(acc[r][1] + bv.y) + y[r][1];
            y[r][2] = tanhf(acc[r][2] + bv.z) + y[r][2];
            y[r][3] = tanhf(acc[r][3] + bv.w) + y[r][3];
        }
    }

    // ---------- head: dump Y to LDS, per-row fp32 chain, f64 signed sum ----
    __syncthreads();                 // all sW reads done; smem becomes Y dump
    #pragma unroll
    for (int r = 0; r < RPW; ++r) {
        int row = r0 + r;
        smem[row * 257 + 4 * lane + 0] = y[r][0];
        smem[row * 257 + 4 * lane + 1] = y[r][1];
        smem[row * 257 + 4 * lane + 2] = y[r][2];
        smem[row * 257 + 4 * lane + 3] = y[r][3];
    }
    __syncthreads();
    double contrib = 0.0;
    if (t < RPB) {
        const float* yrow = &smem[t * 257];
        float f = 0.f;
        #pragma unroll 8
        for (int k = 0; k < ND; ++k) f = fmaf(yrow[k], sWf[k], f);
        f += bf[0];
        int pp = (gr0 + t) % ROWS_PER_B;
        contrib = (double)(c_S[pp / 24] * c_S[pp % 24]) * (double)f;
    }
    if (wv == 0) {
        #pragma unroll
        for (int off = 32; off > 0; off >>= 1) contrib += __shfl_xor(contrib, off, 64);
        if (lane == 0) atomicAdd(&anti[b], contrib);
    }
}

__global__ void finalize_log(const double* __restrict__ anti, float* __restrict__ out) {
    int i = blockIdx.x * 256 + threadIdx.x;
    if (i < BATCH) out[i] = (float)log(fabs(anti[i]));
}

extern "C" void kernel_launch(void* const* d_in, const int* in_sizes, int n_in,
                              void* d_out, int out_size, void* d_ws, size_t ws_size,
                              hipStream_t stream) {
    const float* x1 = (const float*)d_in[0];
    const float* x2 = (const float*)d_in[1];
    const float* W0 = (const float*)d_in[2];
    const float* b0 = (const float*)d_in[3];
    const float* W1 = (const float*)d_in[4];
    const float* b1 = (const float*)d_in[5];
    const float* W2 = (const float*)d_in[6];
    const float* b2 = (const float*)d_in[7];
    const float* Wf = (const float*)d_in[8];
    const float* bf = (const float*)d_in[9];
    double* anti = (double*)d_ws;                   // 512 doubles of scratch
    float* out   = (float*)d_out;

    (void)hipMemsetAsync(anti, 0, BATCH * sizeof(double), stream);
    fused_resnet<<<NBLOCKS, 256, 0, stream>>>(x1, x2, W0, b0, W1, b1, W2, b2, Wf, bf, anti);
    finalize_log<<<(BATCH + 255) / 256, 256, 0, stream>>>(anti, out);
}

// Round 8
// 1259.309 us; speedup vs baseline: 1.5218x; 1.0736x over previous
//
#include <hip/hip_runtime.h>
#include <math.h>

#define ND 256
#define RPB 32            // rows per block (32 | 576 via 9216 blocks)
#define RPW 8             // rows per wave (4 waves)
#define ROWS_PER_B 576
#define BATCH 512
#define NBLOCKS (BATCH * ROWS_PER_B / RPB)   // 9216
#define YSTR 264          // sY row stride in f32 (1056 B, 16B-aligned)

// itertools.permutations(range(4)) — lexicographic order, with parity signs
__constant__ int c_P[24 * 4] = {
    0,1,2,3, 0,1,3,2, 0,2,1,3, 0,2,3,1, 0,3,1,2, 0,3,2,1,
    1,0,2,3, 1,0,3,2, 1,2,0,3, 1,2,3,0, 1,3,0,2, 1,3,2,0,
    2,0,1,3, 2,0,3,1, 2,1,0,3, 2,1,3,0, 2,3,0,1, 2,3,1,0,
    3,0,1,2, 3,0,2,1, 3,1,0,2, 3,1,2,0, 3,2,0,1, 3,2,1,0
};
__constant__ float c_S[24] = {
     1.f,-1.f,-1.f, 1.f, 1.f,-1.f,
    -1.f, 1.f, 1.f,-1.f,-1.f, 1.f,
     1.f,-1.f,-1.f, 1.f, 1.f,-1.f,
    -1.f, 1.f, 1.f,-1.f,-1.f, 1.f
};

// Y lives in LDS per-wave-private rows; y[row][k] is read with a UNIFORM
// address -> hardware broadcast (no VALU, no bank conflict), replacing
// round-7's 32 readlanes per k4-step (23% of VALU + hidden AGPR moves).
// W tile = 16 K-rows (16 KB); total LDS 54,272 B -> 3 blocks/CU, 12 waves.
// fp32 fmaf chain order identical to the passing round-7 kernel.
__global__ __launch_bounds__(256, 2)
void fused_resnet(const float* __restrict__ x1, const float* __restrict__ x2,
                  const float* __restrict__ W0, const float* __restrict__ b0,
                  const float* __restrict__ W1, const float* __restrict__ b1,
                  const float* __restrict__ W2, const float* __restrict__ b2,
                  const float* __restrict__ Wf, const float* __restrict__ bf,
                  double* __restrict__ anti)
{
    __shared__ __align__(16) float smem[13568];  // 54,272 B
    float* sW  = smem;            // [16][256] W tile (16 KB)
    float* sY  = smem + 4096;     // [32][264] f32 activations (33 KB)
    float* sF  = smem + 12544;    // [32][24] feats (L0 only)
    float* sWf = smem + 13312;    // [256] head weights
    // L0 stages W0 (24x256) into the sY region (Y not yet live).

    const int t    = threadIdx.x;
    const int lane = t & 63;
    const int wv   = t >> 6;          // wave 0..3
    const int r0   = wv * RPW;        // this wave's first row
    const int gr0  = blockIdx.x * RPB;
    const int b    = gr0 / ROWS_PER_B;

    // ---- feats into sF; W0 into sY-region; Wf into sWf ----
    for (int i = t; i < RPB * 24; i += 256) {
        int lr = i / 24, c = i % 24;
        int pp = (gr0 + lr) % ROWS_PER_B;
        float v;
        if (c < 12) {
            v = x1[b * 12 + c_P[(pp / 24) * 4 + c / 3] * 3 + (c % 3)];
        } else {
            int cc = c - 12;
            v = x2[b * 12 + c_P[(pp % 24) * 4 + cc / 3] * 3 + (cc % 3)];
        }
        sF[i] = v;
    }
    {   // stage W0 (24 rows = 6144 f32) into sY region
        const float4* src = (const float4*)W0;
        float4* dst = (float4*)sY;
        #pragma unroll
        for (int i = 0; i < 6; ++i) dst[t + 256 * i] = src[t + 256 * i];
    }
    if (t < 64) ((float4*)sWf)[t] = ((const float4*)Wf)[t];
    __syncthreads();

    float acc[RPW][4];   // this lane's cols 4*lane..4*lane+3 of its wave's rows
    float y[RPW][4];     // register copy for residual adds

    // ---------- layer 0: 24 -> 256, tanh, no residual ----------
    #pragma unroll
    for (int r = 0; r < RPW; ++r) { acc[r][0]=0.f; acc[r][1]=0.f; acc[r][2]=0.f; acc[r][3]=0.f; }
    #pragma unroll 1
    for (int k4 = 0; k4 < 6; ++k4) {
        const float4* wp = (const float4*)&sY[(k4 * 4) * ND] + lane;
        float4 w0 = wp[0], w1 = wp[64], w2 = wp[128], w3 = wp[192];
        #pragma unroll
        for (int r = 0; r < RPW; ++r) {
            float4 yv = *(const float4*)&sF[(r0 + r) * 24 + k4 * 4];   // uniform
            acc[r][0] = fmaf(yv.x, w0.x, acc[r][0]);
            acc[r][1] = fmaf(yv.x, w0.y, acc[r][1]);
            acc[r][2] = fmaf(yv.x, w0.z, acc[r][2]);
            acc[r][3] = fmaf(yv.x, w0.w, acc[r][3]);
            acc[r][0] = fmaf(yv.y, w1.x, acc[r][0]);
            acc[r][1] = fmaf(yv.y, w1.y, acc[r][1]);
            acc[r][2] = fmaf(yv.y, w1.z, acc[r][2]);
            acc[r][3] = fmaf(yv.y, w1.w, acc[r][3]);
            acc[r][0] = fmaf(yv.z, w2.x, acc[r][0]);
            acc[r][1] = fmaf(yv.z, w2.y, acc[r][1]);
            acc[r][2] = fmaf(yv.z, w2.z, acc[r][2]);
            acc[r][3] = fmaf(yv.z, w2.w, acc[r][3]);
            acc[r][0] = fmaf(yv.w, w3.x, acc[r][0]);
            acc[r][1] = fmaf(yv.w, w3.y, acc[r][1]);
            acc[r][2] = fmaf(yv.w, w3.z, acc[r][2]);
            acc[r][3] = fmaf(yv.w, w3.w, acc[r][3]);
        }
    }
    __syncthreads();     // all waves done reading W0 from sY region
    {
        float4 bv = *(const float4*)&b0[4 * lane];
        #pragma unroll
        for (int r = 0; r < RPW; ++r) {
            y[r][0] = tanhf(acc[r][0] + bv.x);
            y[r][1] = tanhf(acc[r][1] + bv.y);
            y[r][2] = tanhf(acc[r][2] + bv.z);
            y[r][3] = tanhf(acc[r][3] + bv.w);
            float4 o; o.x = y[r][0]; o.y = y[r][1]; o.z = y[r][2]; o.w = y[r][3];
            *(float4*)&sY[(r0 + r) * YSTR + 4 * lane] = o;   // wave-private rows
        }
    }

    // ---------- layers 1,2: 256 -> 256, tanh + residual ----------
    #pragma unroll 1
    for (int L = 0; L < 2; ++L) {
        const float* __restrict__ Wg = L ? W2 : W1;
        const float* __restrict__ bp = L ? b2 : b1;
        #pragma unroll
        for (int r = 0; r < RPW; ++r) { acc[r][0]=0.f; acc[r][1]=0.f; acc[r][2]=0.f; acc[r][3]=0.f; }
        #pragma unroll 1
        for (int T = 0; T < 16; ++T) {         // 16 K-rows per tile
            __syncthreads();                   // prior tile reads done
            {
                const float4* src = (const float4*)(Wg + T * 16 * ND);
                float4* dst = (float4*)sW;
                #pragma unroll
                for (int i = 0; i < 4; ++i) dst[t + 256 * i] = src[t + 256 * i];
            }
            __syncthreads();
            #pragma unroll
            for (int q = 0; q < 4; ++q) {      // fully unrolled: imm offsets
                const float4* wp = (const float4*)&sW[(q * 4) * ND] + lane;
                float4 w0 = wp[0], w1 = wp[64], w2 = wp[128], w3 = wp[192];
                const int kt = T * 16 + q * 4;
                #pragma unroll
                for (int r = 0; r < RPW; ++r) {
                    float4 yv = *(const float4*)&sY[(r0 + r) * YSTR + kt]; // uniform
                    acc[r][0] = fmaf(yv.x, w0.x, acc[r][0]);
                    acc[r][1] = fmaf(yv.x, w0.y, acc[r][1]);
                    acc[r][2] = fmaf(yv.x, w0.z, acc[r][2]);
                    acc[r][3] = fmaf(yv.x, w0.w, acc[r][3]);
                    acc[r][0] = fmaf(yv.y, w1.x, acc[r][0]);
                    acc[r][1] = fmaf(yv.y, w1.y, acc[r][1]);
                    acc[r][2] = fmaf(yv.y, w1.z, acc[r][2]);
                    acc[r][3] = fmaf(yv.y, w1.w, acc[r][3]);
                    acc[r][0] = fmaf(yv.z, w2.x, acc[r][0]);
                    acc[r][1] = fmaf(yv.z, w2.y, acc[r][1]);
                    acc[r][2] = fmaf(yv.z, w2.z, acc[r][2]);
                    acc[r][3] = fmaf(yv.z, w2.w, acc[r][3]);
                    acc[r][0] = fmaf(yv.w, w3.x, acc[r][0]);
                    acc[r][1] = fmaf(yv.w, w3.y, acc[r][1]);
                    acc[r][2] = fmaf(yv.w, w3.z, acc[r][2]);
                    acc[r][3] = fmaf(yv.w, w3.w, acc[r][3]);
                }
            }
        }
        float4 bv = *(const float4*)&bp[4 * lane];
        #pragma unroll
        for (int r = 0; r < RPW; ++r) {
            y[r][0] = tanhf(acc[r][0] + bv.x) + y[r][0];
            y[r][1] = tanhf(acc[r][1] + bv.y) + y[r][1];
            y[r][2] = tanhf(acc[r][2] + bv.z) + y[r][2];
            y[r][3] = tanhf(acc[r][3] + bv.w) + y[r][3];
            float4 o; o.x = y[r][0]; o.y = y[r][1]; o.z = y[r][2]; o.w = y[r][3];
            *(float4*)&sY[(r0 + r) * YSTR + 4 * lane] = o;   // wave-private rows
        }
    }

    // ---------- head: per-row fp32 chain from sY, f64 signed sum ----------
    __syncthreads();                 // cross-wave row reads below
    double contrib = 0.0;
    if (t < RPB) {
        const float* yrow = &sY[t * YSTR];
        float f = 0.f;
        #pragma unroll 8
        for (int k = 0; k < ND; ++k) f = fmaf(yrow[k], sWf[k], f);
        f += bf[0];
        int pp = (gr0 + t) % ROWS_PER_B;
        contrib = (double)(c_S[pp / 24] * c_S[pp % 24]) * (double)f;
    }
    if (wv == 0) {
        #pragma unroll
        for (int off = 32; off > 0; off >>= 1) contrib += __shfl_xor(contrib, off, 64);
        if (lane == 0) atomicAdd(&anti[b], contrib);
    }
}

__global__ void finalize_log(const double* __restrict__ anti, float* __restrict__ out) {
    int i = blockIdx.x * 256 + threadIdx.x;
    if (i < BATCH) out[i] = (float)log(fabs(anti[i]));
}

extern "C" void kernel_launch(void* const* d_in, const int* in_sizes, int n_in,
                              void* d_out, int out_size, void* d_ws, size_t ws_size,
                              hipStream_t stream) {
    const float* x1 = (const float*)d_in[0];
    const float* x2 = (const float*)d_in[1];
    const float* W0 = (const float*)d_in[2];
    const float* b0 = (const float*)d_in[3];
    const float* W1 = (const float*)d_in[4];
    const float* b1 = (const float*)d_in[5];
    const float* W2 = (const float*)d_in[6];
    const float* b2 = (const float*)d_in[7];
    const float* Wf = (const float*)d_in[8];
    const float* bf = (const float*)d_in[9];
    double* anti = (double*)d_ws;                   // 512 doubles of scratch
    float* out   = (float*)d_out;

    (void)hipMemsetAsync(anti, 0, BATCH * sizeof(double), stream);
    fused_resnet<<<NBLOCKS, 256, 0, stream>>>(x1, x2, W0, b0, W1, b1, W2, b2, Wf, bf, anti);
    finalize_log<<<(BATCH + 255) / 256, 256, 0, stream>>>(anti, out);
}

// Round 9
// 1194.055 us; speedup vs baseline: 1.6050x; 1.0546x over previous
//
#include <hip/hip_runtime.h>
#include <math.h>

#define ND 256
#define RPB 32            // rows per block (32 | 576 via 9216 blocks)
#define RPW 8             // rows per wave (4 waves)
#define ROWS_PER_B 576
#define BATCH 512
#define NBLOCKS (BATCH * ROWS_PER_B / RPB)   // 9216
#define YSTR 256          // sY row stride (head's 32-way conflict is one-time)

// itertools.permutations(range(4)) — lexicographic order, with parity signs
__constant__ int c_P[24 * 4] = {
    0,1,2,3, 0,1,3,2, 0,2,1,3, 0,2,3,1, 0,3,1,2, 0,3,2,1,
    1,0,2,3, 1,0,3,2, 1,2,0,3, 1,2,3,0, 1,3,0,2, 1,3,2,0,
    2,0,1,3, 2,0,3,1, 2,1,0,3, 2,1,3,0, 2,3,0,1, 2,3,1,0,
    3,0,1,2, 3,0,2,1, 3,1,0,2, 3,1,2,0, 3,2,0,1, 3,2,1,0
};
__constant__ float c_S[24] = {
     1.f,-1.f,-1.f, 1.f, 1.f,-1.f,
    -1.f, 1.f, 1.f,-1.f,-1.f, 1.f,
     1.f,-1.f,-1.f, 1.f, 1.f,-1.f,
    -1.f, 1.f, 1.f,-1.f,-1.f, 1.f
};

// Structure: Y in LDS, read via UNIFORM ds_read_b128 (hardware broadcast, no
// VALU cost) — r8's lean mix.  LDS trimmed to 40,960 B so 4 blocks/CU fit
// (r8's 54 KB gave only 2 blocks -> VALUBusy 63%).  Next W tile is prefetched
// into 2 float4 regs during the current tile's FMAs (live set ~110 < 128, the
// r6 spill cliff).  fp32 fmaf chain order identical to passing r7/r8.
__global__ __launch_bounds__(256, 4)
void fused_resnet(const float* __restrict__ x1, const float* __restrict__ x2,
                  const float* __restrict__ W0, const float* __restrict__ b0,
                  const float* __restrict__ W1, const float* __restrict__ b1,
                  const float* __restrict__ W2, const float* __restrict__ b2,
                  const float* __restrict__ Wf, const float* __restrict__ bf,
                  double* __restrict__ anti)
{
    __shared__ __align__(16) float smem[10240];  // 40,960 B total
    float* sW = smem;             // [8][256] W tile (8 KB); L0: feats; head: Wf
    float* sY = smem + 2048;      // [32][256] f32 activations (32 KB)
    // L0 stages W0 (24x256 = 24 KB) into the sY region (Y not yet live);
    // feats (3 KB) live in the sW region during L0.

    const int t    = threadIdx.x;
    const int lane = t & 63;
    const int wv   = t >> 6;          // wave 0..3
    const int r0   = wv * RPW;        // this wave's first row
    const int gr0  = blockIdx.x * RPB;
    const int b    = gr0 / ROWS_PER_B;

    // ---- feats into sW region; W0 into sY region ----
    for (int i = t; i < RPB * 24; i += 256) {
        int lr = i / 24, c = i % 24;
        int pp = (gr0 + lr) % ROWS_PER_B;
        float v;
        if (c < 12) {
            v = x1[b * 12 + c_P[(pp / 24) * 4 + c / 3] * 3 + (c % 3)];
        } else {
            int cc = c - 12;
            v = x2[b * 12 + c_P[(pp % 24) * 4 + cc / 3] * 3 + (cc % 3)];
        }
        sW[i] = v;
    }
    {   // stage W0 (24 rows = 6144 f32) into sY region
        const float4* src = (const float4*)W0;
        float4* dst = (float4*)sY;
        #pragma unroll
        for (int i = 0; i < 6; ++i) dst[t + 256 * i] = src[t + 256 * i];
    }
    __syncthreads();

    float acc[RPW][4];   // this lane's cols 4*lane..4*lane+3 of its wave's rows
    float y[RPW][4];     // register copy for residual adds

    // ---------- layer 0: 24 -> 256, tanh, no residual ----------
    #pragma unroll
    for (int r = 0; r < RPW; ++r) { acc[r][0]=0.f; acc[r][1]=0.f; acc[r][2]=0.f; acc[r][3]=0.f; }
    #pragma unroll 1
    for (int k4 = 0; k4 < 6; ++k4) {
        const float4* wp = (const float4*)&sY[(k4 * 4) * ND] + lane;
        float4 w0 = wp[0], w1 = wp[64], w2 = wp[128], w3 = wp[192];
        #pragma unroll
        for (int r = 0; r < RPW; ++r) {
            float4 yv = *(const float4*)&sW[(r0 + r) * 24 + k4 * 4];   // uniform
            acc[r][0] = fmaf(yv.x, w0.x, acc[r][0]);
            acc[r][1] = fmaf(yv.x, w0.y, acc[r][1]);
            acc[r][2] = fmaf(yv.x, w0.z, acc[r][2]);
            acc[r][3] = fmaf(yv.x, w0.w, acc[r][3]);
            acc[r][0] = fmaf(yv.y, w1.x, acc[r][0]);
            acc[r][1] = fmaf(yv.y, w1.y, acc[r][1]);
            acc[r][2] = fmaf(yv.y, w1.z, acc[r][2]);
            acc[r][3] = fmaf(yv.y, w1.w, acc[r][3]);
            acc[r][0] = fmaf(yv.z, w2.x, acc[r][0]);
            acc[r][1] = fmaf(yv.z, w2.y, acc[r][1]);
            acc[r][2] = fmaf(yv.z, w2.z, acc[r][2]);
            acc[r][3] = fmaf(yv.z, w2.w, acc[r][3]);
            acc[r][0] = fmaf(yv.w, w3.x, acc[r][0]);
            acc[r][1] = fmaf(yv.w, w3.y, acc[r][1]);
            acc[r][2] = fmaf(yv.w, w3.z, acc[r][2]);
            acc[r][3] = fmaf(yv.w, w3.w, acc[r][3]);
        }
    }
    __syncthreads();     // all waves done reading W0-in-sY and feats-in-sW
    {
        float4 bv = *(const float4*)&b0[4 * lane];
        #pragma unroll
        for (int r = 0; r < RPW; ++r) {
            y[r][0] = tanhf(acc[r][0] + bv.x);
            y[r][1] = tanhf(acc[r][1] + bv.y);
            y[r][2] = tanhf(acc[r][2] + bv.z);
            y[r][3] = tanhf(acc[r][3] + bv.w);
            float4 o; o.x = y[r][0]; o.y = y[r][1]; o.z = y[r][2]; o.w = y[r][3];
            *(float4*)&sY[(r0 + r) * YSTR + 4 * lane] = o;   // wave-private rows
        }
    }

    // ---------- layers 1,2: 256 -> 256, tanh + residual ----------
    #pragma unroll 1
    for (int L = 0; L < 2; ++L) {
        const float* __restrict__ Wg = L ? W2 : W1;
        const float* __restrict__ bp = L ? b2 : b1;
        const float4* src = (const float4*)Wg;
        #pragma unroll
        for (int r = 0; r < RPW; ++r) { acc[r][0]=0.f; acc[r][1]=0.f; acc[r][2]=0.f; acc[r][3]=0.f; }
        float4 g0 = src[t], g1 = src[t + 256];         // tile 0 in regs
        #pragma unroll 1
        for (int T = 0; T < 32; ++T) {                 // 8 K-rows per tile
            __syncthreads();                           // prior tile reads done
            ((float4*)sW)[t] = g0;
            ((float4*)sW)[t + 256] = g1;
            if (T < 31) {                              // prefetch next tile
                g0 = src[(T + 1) * 512 + t];
                g1 = src[(T + 1) * 512 + t + 256];
            }
            __syncthreads();                           // sW tile T ready
            #pragma unroll
            for (int q = 0; q < 2; ++q) {
                const float4* wp = (const float4*)&sW[(q * 4) * ND] + lane;
                float4 w0 = wp[0], w1 = wp[64], w2 = wp[128], w3 = wp[192];
                const int kt = T * 8 + q * 4;
                #pragma unroll
                for (int r = 0; r < RPW; ++r) {
                    float4 yv = *(const float4*)&sY[(r0 + r) * YSTR + kt]; // uniform
                    acc[r][0] = fmaf(yv.x, w0.x, acc[r][0]);
                    acc[r][1] = fmaf(yv.x, w0.y, acc[r][1]);
                    acc[r][2] = fmaf(yv.x, w0.z, acc[r][2]);
                    acc[r][3] = fmaf(yv.x, w0.w, acc[r][3]);
                    acc[r][0] = fmaf(yv.y, w1.x, acc[r][0]);
                    acc[r][1] = fmaf(yv.y, w1.y, acc[r][1]);
                    acc[r][2] = fmaf(yv.y, w1.z, acc[r][2]);
                    acc[r][3] = fmaf(yv.y, w1.w, acc[r][3]);
                    acc[r][0] = fmaf(yv.z, w2.x, acc[r][0]);
                    acc[r][1] = fmaf(yv.z, w2.y, acc[r][1]);
                    acc[r][2] = fmaf(yv.z, w2.z, acc[r][2]);
                    acc[r][3] = fmaf(yv.z, w2.w, acc[r][3]);
                    acc[r][0] = fmaf(yv.w, w3.x, acc[r][0]);
                    acc[r][1] = fmaf(yv.w, w3.y, acc[r][1]);
                    acc[r][2] = fmaf(yv.w, w3.z, acc[r][2]);
                    acc[r][3] = fmaf(yv.w, w3.w, acc[r][3]);
                }
            }
        }
        float4 bv = *(const float4*)&bp[4 * lane];
        #pragma unroll
        for (int r = 0; r < RPW; ++r) {
            y[r][0] = tanhf(acc[r][0] + bv.x) + y[r][0];
            y[r][1] = tanhf(acc[r][1] + bv.y) + y[r][1];
            y[r][2] = tanhf(acc[r][2] + bv.z) + y[r][2];
            y[r][3] = tanhf(acc[r][3] + bv.w) + y[r][3];
            float4 o; o.x = y[r][0]; o.y = y[r][1]; o.z = y[r][2]; o.w = y[r][3];
            *(float4*)&sY[(r0 + r) * YSTR + 4 * lane] = o;   // wave-private rows
        }
    }

    // ---------- head: stage Wf into sW, per-row fp32 chain, f64 sum -------
    __syncthreads();                 // all sW reads + sY writes complete
    if (t < 64) ((float4*)sW)[t] = ((const float4*)Wf)[t];
    __syncthreads();
    double contrib = 0.0;
    if (t < RPB) {
        const float* yrow = &sY[t * YSTR];
        float f = 0.f;
        #pragma unroll 8
        for (int k = 0; k < ND; ++k) f = fmaf(yrow[k], sW[k], f);
        f += bf[0];
        int pp = (gr0 + t) % ROWS_PER_B;
        contrib = (double)(c_S[pp / 24] * c_S[pp % 24]) * (double)f;
    }
    if (wv == 0) {
        #pragma unroll
        for (int off = 32; off > 0; off >>= 1) contrib += __shfl_xor(contrib, off, 64);
        if (lane == 0) atomicAdd(&anti[b], contrib);
    }
}

__global__ void finalize_log(const double* __restrict__ anti, float* __restrict__ out) {
    int i = blockIdx.x * 256 + threadIdx.x;
    if (i < BATCH) out[i] = (float)log(fabs(anti[i]));
}

extern "C" void kernel_launch(void* const* d_in, const int* in_sizes, int n_in,
                              void* d_out, int out_size, void* d_ws, size_t ws_size,
                              hipStream_t stream) {
    const float* x1 = (const float*)d_in[0];
    const float* x2 = (const float*)d_in[1];
    const float* W0 = (const float*)d_in[2];
    const float* b0 = (const float*)d_in[3];
    const float* W1 = (const float*)d_in[4];
    const float* b1 = (const float*)d_in[5];
    const float* W2 = (const float*)d_in[6];
    const float* b2 = (const float*)d_in[7];
    const float* Wf = (const float*)d_in[8];
    const float* bf = (const float*)d_in[9];
    double* anti = (double*)d_ws;                   // 512 doubles of scratch
    float* out   = (float*)d_out;

    (void)hipMemsetAsync(anti, 0, BATCH * sizeof(double), stream);
    fused_resnet<<<NBLOCKS, 256, 0, stream>>>(x1, x2, W0, b0, W1, b1, W2, b2, Wf, bf, anti);
    finalize_log<<<(BATCH + 255) / 256, 256, 0, stream>>>(anti, out);
}